// Round 3
// baseline (161.464 us; speedup 1.0000x reference)
//
#include <hip/hip_runtime.h>
#include <hip/hip_bf16.h>
#include <stdint.h>

// Problem constants
#define B_ 4
#define L_ 1024
#define D_ 768
#define H_ 12
#define HD_ 64
#define M_ 4096     // B*L
#define N3_ 2304    // 3*D

typedef float f32x4 __attribute__((ext_vector_type(4)));
typedef float f32x4v __attribute__((ext_vector_type(4)));
typedef short bf16x8 __attribute__((ext_vector_type(8)));
typedef unsigned short u16;
typedef u16 u16x8 __attribute__((ext_vector_type(8)));
typedef u16 u16x4 __attribute__((ext_vector_type(4)));
typedef uint32_t u32x2 __attribute__((ext_vector_type(2)));

#define AS3 __attribute__((address_space(3)))
#define AS1 __attribute__((address_space(1)))

__device__ __forceinline__ void gll16(const void* g, void* l) {
  __builtin_amdgcn_global_load_lds((const AS1 void*)g, (AS3 void*)l, 16, 0, 0);
}

// fp32 -> bf16 round-to-nearest-even (finite data)
__device__ __forceinline__ u16 f2bf(float f) {
  uint32_t u = __builtin_bit_cast(uint32_t, f);
  u += 0x7fffu + ((u >> 16) & 1u);
  return (u16)(u >> 16);
}

// ---------------- fused conversion kernel (3 tensors, fp32 -> bf16) ---------
__global__ void k_cvt3(const float* __restrict__ a, u16* __restrict__ ao, int na4,
                       const float* __restrict__ b, u16* __restrict__ bo, int nb4,
                       const float* __restrict__ c, u16* __restrict__ co, int nc4) {
  int i = blockIdx.x * 256 + threadIdx.x;
  const float* src;
  u16* dst;
  if (i < na4) {
    src = a; dst = ao;
  } else if (i < na4 + nb4) {
    src = b; dst = bo; i -= na4;
  } else if (i < na4 + nb4 + nc4) {
    src = c; dst = co; i -= na4 + nb4;
  } else {
    return;
  }
  f32x4v v = ((const f32x4v*)src)[i];
  u16x4 o;
  o.x = f2bf(v.x); o.y = f2bf(v.y); o.z = f2bf(v.z); o.w = f2bf(v.w);
  ((u16x4*)dst)[i] = o;
}

// ---------------- GEMM1: qkv = x @ w_in^T + b_in -> Q,K,V bf16 [B,H,L,64] ----
__global__ __launch_bounds__(256) void k_gemm_qkv(
    const u16* __restrict__ Xb, const u16* __restrict__ Wb,
    const float* __restrict__ b_in,
    u16* __restrict__ gQ, u16* __restrict__ gK, u16* __restrict__ gV) {
  __shared__ u16 As[128 * 64];
  __shared__ u16 Bs[128 * 64];
  const int tid = threadIdx.x;
  const int lane = tid & 63;
  const int w = tid >> 6;
  const int wm = (w >> 1) * 64;
  const int wn = (w & 1) * 64;
  const int lr = lane & 15;
  const int lg = lane >> 4;
  const int m0 = blockIdx.x * 128;
  const int n0 = blockIdx.y * 128;

  f32x4 acc[4][4];
#pragma unroll
  for (int i = 0; i < 4; ++i)
#pragma unroll
    for (int j = 0; j < 4; ++j) acc[i][j] = (f32x4){0.f, 0.f, 0.f, 0.f};

  for (int kt = 0; kt < 12; ++kt) {
    __syncthreads();
#pragma unroll
    for (int i = 0; i < 4; ++i) {
      int seg = i * 256 + tid;
      int row = seg >> 3;
      int sl = (seg & 7) ^ (row & 7);
      gll16(Xb + (size_t)(m0 + row) * 768 + kt * 64 + sl * 8, (char*)As + seg * 16);
      gll16(Wb + (size_t)(n0 + row) * 768 + kt * 64 + sl * 8, (char*)Bs + seg * 16);
    }
    __syncthreads();
#pragma unroll
    for (int kh = 0; kh < 2; ++kh) {
      bf16x8 af[4], bfr[4];
#pragma unroll
      for (int t = 0; t < 4; ++t) {
        int ra = wm + t * 16 + lr;
        af[t] = *(const bf16x8*)((const char*)As + ra * 128 +
                                 ((kh * 64 + lg * 16) ^ ((ra & 7) << 4)));
        int rb = wn + t * 16 + lr;
        bfr[t] = *(const bf16x8*)((const char*)Bs + rb * 128 +
                                  ((kh * 64 + lg * 16) ^ ((rb & 7) << 4)));
      }
#pragma unroll
      for (int mi = 0; mi < 4; ++mi)
#pragma unroll
        for (int ni = 0; ni < 4; ++ni)
          acc[mi][ni] = __builtin_amdgcn_mfma_f32_16x16x32_bf16(
              af[mi], bfr[ni], acc[mi][ni], 0, 0, 0);
    }
  }
  // epilogue: +b_in, scale q, scatter to [B,H,L,64] bf16
  const int sec = blockIdx.y / 6;  // 0=q,1=k,2=v
  u16* dst = sec == 0 ? gQ : (sec == 1 ? gK : gV);
  const float scale = sec == 0 ? 0.125f : 1.0f;
#pragma unroll
  for (int ni = 0; ni < 4; ++ni) {
    int e = n0 + wn + ni * 16 + lr;  // 0..2303
    float bias = b_in[e];
    int es = e - sec * 768;
    int h = es >> 6, d = es & 63;
#pragma unroll
    for (int mi = 0; mi < 4; ++mi) {
#pragma unroll
      for (int j = 0; j < 4; ++j) {
        int m = m0 + wm + mi * 16 + lg * 4 + j;
        int bb = m >> 10, lq = m & 1023;
        float vv = (acc[mi][ni][j] + bias) * scale;
        dst[(size_t)((bb * 12 + h) * 1024 + lq) * 64 + d] = f2bf(vv);
      }
    }
  }
}

// ---------------- V transpose: [B,H,L,64] -> [B,H,64,L] ---------------------
__global__ __launch_bounds__(256) void k_transpose(const u16* __restrict__ V,
                                                   u16* __restrict__ Vt) {
  __shared__ u16 t[64][66];
  const int tid = threadIdx.x;
  const int bh = blockIdx.x >> 4;
  const int kv0 = (blockIdx.x & 15) * 64;
  {
    int r = tid >> 2, c0 = (tid & 3) * 16;
    const u16* src = V + (size_t)(bh * 1024 + kv0 + r) * 64 + c0;
#pragma unroll
    for (int p = 0; p < 2; ++p) {
      u16x8 x = *(const u16x8*)(src + p * 8);
#pragma unroll
      for (int e = 0; e < 8; ++e) t[r][c0 + p * 8 + e] = x[e];
    }
  }
  __syncthreads();
  {
    int d = tid >> 2, k0 = (tid & 3) * 16;
    u16* dst = Vt + (size_t)(bh * 64 + d) * 1024 + kv0 + k0;
#pragma unroll
    for (int p = 0; p < 2; ++p) {
      u16x8 o;
#pragma unroll
      for (int e = 0; e < 8; ++e) o[e] = t[k0 + p * 8 + e][d];
      *(u16x8*)(dst + p * 8) = o;
    }
  }
}

// ---------------- fused flash attention (swapped QK^T, lane-local softmax) --
// S^T = mfma(K, Q): lane holds P[q = lane&15][kv = ni*16 + lg*4 + j].
// Softmax: 15 in-lane ops + shfl_xor(16,32). Bias staged via async gll16
// (double-buffered LDS, source pre-swizzled). K/V read direct from L2 into
// registers (q-independent fragments; 4 waves share via L1). One barrier/tile.
__global__ __launch_bounds__(256) void k_attn(
    const u16* __restrict__ gQ, const u16* __restrict__ gK,
    const u16* __restrict__ gVt, const float* __restrict__ gBias,
    u16* __restrict__ gO) {
  __shared__ f32x4 biasS[2][1024];  // 2 x 16KB, [64 q][16 slots of 4 floats]
  __shared__ f32x4 PlV[4][128];     // per-wave 2KB P bounce (16B aligned)
  const int tid = threadIdx.x;
  const int lane = tid & 63;
  const int w = tid >> 6;
  const int lr = lane & 15;
  const int lg = lane >> 4;
  // XCD-bijective swizzle: 768 = 8 XCDs x 96 consecutive; groups the 16
  // q-blocks sharing one (b,h)'s K/V onto one XCD for L2 residency.
  const int lb = (blockIdx.x & 7) * 96 + (blockIdx.x >> 3);
  const int bh = lb >> 4;
  const int q0 = (lb & 15) * 64;
  const int qr = q0 + w * 16;  // wave's q-row base; lane's q-row = qr + lr

// bias tile stage: 64 q-rows x 64 kv fp32, LDS slot s holds kv-chunk (s^(q&7))
#define STAGE_BIAS(buf, kv0)                                                  \
  do {                                                                        \
    _Pragma("unroll") for (int i_ = 0; i_ < 4; ++i_) {                        \
      int seg_ = i_ * 256 + tid;                                              \
      int qrow_ = seg_ >> 4;                                                  \
      int c_ = (seg_ & 15) ^ (qrow_ & 7);                                     \
      gll16(gBias + (size_t)(bh * 1024 + q0 + qrow_) * 1024 + (kv0) + c_ * 4, \
            (char*)biasS + (buf) * 16384 + seg_ * 16);                        \
    }                                                                         \
  } while (0)

  // Q as B-operand: rows q = qr+lr, k contiguous-8 at kh*32+lg*8 (pre-scaled)
  bf16x8 qa[2];
#pragma unroll
  for (int kh = 0; kh < 2; ++kh)
    qa[kh] = *(const bf16x8*)(gQ + (size_t)(bh * 1024 + qr + lr) * 64 + kh * 32 + lg * 8);

  f32x4 oacc[4];
#pragma unroll
  for (int dt = 0; dt < 4; ++dt) oacc[dt] = (f32x4){0.f, 0.f, 0.f, 0.f};
  float mrow = -1e30f, lrow = 0.f;

  STAGE_BIAS(0, 0);
  __syncthreads();

  char* plw = (char*)PlV[w];
  const int swz = (lr & 7) << 4;

  for (int t = 0; t < 16; ++t) {
    const int cur = t & 1;
    const int kv0 = t * 64;

    // K fragments (A-operand, rows = kv): direct from L1/L2
    bf16x8 kb[2][4];
#pragma unroll
    for (int kh = 0; kh < 2; ++kh)
#pragma unroll
      for (int ni = 0; ni < 4; ++ni)
        kb[kh][ni] = *(const bf16x8*)(
            gK + ((size_t)(bh * 1024 + kv0 + ni * 16 + lr) << 6) + kh * 32 + lg * 8);
    // V^T fragments (B-operand, rows = d): direct from L1/L2
    bf16x8 vb[2][4];
#pragma unroll
    for (int kh = 0; kh < 2; ++kh)
#pragma unroll
      for (int dt = 0; dt < 4; ++dt)
        vb[kh][dt] = *(const bf16x8*)(
            gVt + ((size_t)(bh * 64 + dt * 16 + lr) << 10) + kv0 + kh * 32 + lg * 8);

    if (t < 15) STAGE_BIAS(cur ^ 1, kv0 + 64);  // async, drains at tile-end barrier

    // S^T = K Q^T : s[ni][j] = S[kv = ni*16+lg*4+j][q = qr+lr]
    f32x4 s[4];
#pragma unroll
    for (int ni = 0; ni < 4; ++ni) s[ni] = (f32x4){0.f, 0.f, 0.f, 0.f};
    __builtin_amdgcn_s_setprio(1);
#pragma unroll
    for (int kh = 0; kh < 2; ++kh)
#pragma unroll
      for (int ni = 0; ni < 4; ++ni)
        s[ni] = __builtin_amdgcn_mfma_f32_16x16x32_bf16(kb[kh][ni], qa[kh], s[ni], 0, 0, 0);
    __builtin_amdgcn_s_setprio(0);

    // + bias from LDS (swizzled slots; j maps to consecutive kv = f32x4 lanes)
#pragma unroll
    for (int ni = 0; ni < 4; ++ni) {
      f32x4 bv = *(const f32x4*)((const char*)biasS + cur * 16384 +
                                 (w * 16 + lr) * 256 + (((ni * 4 + lg) ^ (lr & 7)) << 4));
      s[ni] += bv;
    }

    // lane-local online softmax for q-row (qr+lr); 16 values per lane
    float mx0 = fmaxf(fmaxf(s[0][0], s[0][1]), fmaxf(s[0][2], s[0][3]));
    float mx1 = fmaxf(fmaxf(s[1][0], s[1][1]), fmaxf(s[1][2], s[1][3]));
    float mx2 = fmaxf(fmaxf(s[2][0], s[2][1]), fmaxf(s[2][2], s[2][3]));
    float mx3 = fmaxf(fmaxf(s[3][0], s[3][1]), fmaxf(s[3][2], s[3][3]));
    float vmax = fmaxf(fmaxf(mx0, mx1), fmaxf(mx2, mx3));
    vmax = fmaxf(vmax, __shfl_xor(vmax, 16));
    vmax = fmaxf(vmax, __shfl_xor(vmax, 32));
    float mnew = fmaxf(mrow, vmax);
    float al = __expf(mrow - mnew);
    mrow = mnew;
#pragma unroll
    for (int ni = 0; ni < 4; ++ni)
#pragma unroll
      for (int j = 0; j < 4; ++j) s[ni][j] = __expf(s[ni][j] - mnew);
    float r0 = (s[0][0] + s[0][1]) + (s[0][2] + s[0][3]);
    float r1 = (s[1][0] + s[1][1]) + (s[1][2] + s[1][3]);
    float r2 = (s[2][0] + s[2][1]) + (s[2][2] + s[2][3]);
    float r3 = (s[3][0] + s[3][1]) + (s[3][2] + s[3][3]);
    float rs = (r0 + r1) + (r2 + r3);
    rs += __shfl_xor(rs, 16);
    rs += __shfl_xor(rs, 32);
    lrow = lrow * al + rs;

    // broadcast al from lane (lr = q) to the oacc owners (q = lg*4+j)
    f32x4 av;
#pragma unroll
    for (int j = 0; j < 4; ++j) av[j] = __shfl(al, (lane & 48) | (lg * 4 + j));
#pragma unroll
    for (int dt = 0; dt < 4; ++dt) oacc[dt] *= av;

    // P pack -> per-wave swizzled LDS (b64 writes), read back as A-fragment
#pragma unroll
    for (int ni = 0; ni < 4; ++ni) {
      uint32_t w0 = (uint32_t)f2bf(s[ni][0]) | ((uint32_t)f2bf(s[ni][1]) << 16);
      uint32_t w1 = (uint32_t)f2bf(s[ni][2]) | ((uint32_t)f2bf(s[ni][3]) << 16);
      u32x2 pv = {w0, w1};
      *(u32x2*)(plw + lr * 128 + ((ni * 32 + lg * 8) ^ swz)) = pv;
    }
    __builtin_amdgcn_s_setprio(1);
#pragma unroll
    for (int kh = 0; kh < 2; ++kh) {
      bf16x8 pa = *(const bf16x8*)(plw + lr * 128 + ((kh * 64 + lg * 16) ^ swz));
#pragma unroll
      for (int dt = 0; dt < 4; ++dt)
        oacc[dt] = __builtin_amdgcn_mfma_f32_16x16x32_bf16(pa, vb[kh][dt], oacc[dt], 0, 0, 0);
    }
    __builtin_amdgcn_s_setprio(0);

    __syncthreads();  // drains bias gll16 (vmcnt 0) + publishes buf cur^1
  }

  // normalize + store O bf16 [B,L,D]; inv broadcast like al
  float inv = 1.0f / lrow;
  f32x4 iv;
#pragma unroll
  for (int j = 0; j < 4; ++j) iv[j] = __shfl(inv, (lane & 48) | (lg * 4 + j));
  const int bg = bh / 12, h = bh % 12;
#pragma unroll
  for (int j = 0; j < 4; ++j) {
    int row = qr + lg * 4 + j;
#pragma unroll
    for (int dt = 0; dt < 4; ++dt) {
      gO[(size_t)(bg * 1024 + row) * 768 + h * 64 + dt * 16 + lr] =
          f2bf(oacc[dt][j] * iv[j]);
    }
  }
#undef STAGE_BIAS
}

// ---------------- GEMM2: out = O @ w_out^T + b_out (fp32 out), 64x64 tiles --
__global__ __launch_bounds__(256) void k_gemm_out(
    const u16* __restrict__ Ob, const u16* __restrict__ Wb,
    const float* __restrict__ b_out, float* __restrict__ out) {
  __shared__ u16 As[64 * 64];
  __shared__ u16 Bs[64 * 64];
  const int tid = threadIdx.x;
  const int lane = tid & 63;
  const int w = tid >> 6;
  const int wm = (w >> 1) * 32;
  const int wn = (w & 1) * 32;
  const int lr = lane & 15;
  const int lg = lane >> 4;
  const int m0 = blockIdx.x * 64;
  const int n0 = blockIdx.y * 64;

  f32x4 acc[2][2];
#pragma unroll
  for (int i = 0; i < 2; ++i)
#pragma unroll
    for (int j = 0; j < 2; ++j) acc[i][j] = (f32x4){0.f, 0.f, 0.f, 0.f};

  for (int kt = 0; kt < 12; ++kt) {
    __syncthreads();
#pragma unroll
    for (int i = 0; i < 2; ++i) {
      int seg = i * 256 + tid;
      int row = seg >> 3;
      int sl = (seg & 7) ^ (row & 7);
      gll16(Ob + (size_t)(m0 + row) * 768 + kt * 64 + sl * 8, (char*)As + seg * 16);
      gll16(Wb + (size_t)(n0 + row) * 768 + kt * 64 + sl * 8, (char*)Bs + seg * 16);
    }
    __syncthreads();
#pragma unroll
    for (int kh = 0; kh < 2; ++kh) {
      bf16x8 af[2], bfr[2];
#pragma unroll
      for (int t = 0; t < 2; ++t) {
        int ra = wm + t * 16 + lr;
        af[t] = *(const bf16x8*)((const char*)As + ra * 128 +
                                 ((kh * 64 + lg * 16) ^ ((ra & 7) << 4)));
        int rb = wn + t * 16 + lr;
        bfr[t] = *(const bf16x8*)((const char*)Bs + rb * 128 +
                                  ((kh * 64 + lg * 16) ^ ((rb & 7) << 4)));
      }
#pragma unroll
      for (int mi = 0; mi < 2; ++mi)
#pragma unroll
        for (int ni = 0; ni < 2; ++ni)
          acc[mi][ni] = __builtin_amdgcn_mfma_f32_16x16x32_bf16(
              af[mi], bfr[ni], acc[mi][ni], 0, 0, 0);
    }
  }
#pragma unroll
  for (int ni = 0; ni < 2; ++ni) {
    int n = n0 + wn + ni * 16 + lr;
    float bias = b_out[n];
#pragma unroll
    for (int mi = 0; mi < 2; ++mi) {
#pragma unroll
      for (int j = 0; j < 4; ++j) {
        int m = m0 + wm + mi * 16 + lg * 4 + j;
        out[(size_t)m * 768 + n] = acc[mi][ni][j] + bias;
      }
    }
  }
}

extern "C" void kernel_launch(void* const* d_in, const int* in_sizes, int n_in,
                              void* d_out, int out_size, void* d_ws, size_t ws_size,
                              hipStream_t stream) {
  const float* x = (const float*)d_in[0];
  const float* attn_bias = (const float*)d_in[1];
  const float* w_in = (const float*)d_in[2];
  const float* b_in = (const float*)d_in[3];
  const float* w_out = (const float*)d_in[4];
  const float* b_out = (const float*)d_in[5];
  float* out = (float*)d_out;

  char* ws = (char*)d_ws;
  size_t off = 0;
  u16* xb = (u16*)(ws + off);  off += (size_t)M_ * D_ * 2;
  u16* wib = (u16*)(ws + off); off += (size_t)N3_ * D_ * 2;
  u16* wob = (u16*)(ws + off); off += (size_t)D_ * D_ * 2;
  u16* q = (u16*)(ws + off);   off += (size_t)48 * 1024 * 64 * 2;
  u16* k = (u16*)(ws + off);   off += (size_t)48 * 1024 * 64 * 2;
  u16* v = (u16*)(ws + off);   off += (size_t)48 * 1024 * 64 * 2;
  u16* vt = (u16*)(ws + off);  off += (size_t)48 * 1024 * 64 * 2;
  u16* ob = (u16*)(ws + off);  off += (size_t)M_ * D_ * 2;

  const int na4 = (M_ * D_) / 4;
  const int nb4 = (N3_ * D_) / 4;
  const int nc4 = (D_ * D_) / 4;
  k_cvt3<<<(na4 + nb4 + nc4 + 255) / 256, 256, 0, stream>>>(
      x, xb, na4, w_in, wib, nb4, w_out, wob, nc4);
  k_gemm_qkv<<<dim3(32, 18), 256, 0, stream>>>(xb, wib, b_in, q, k, v);
  k_transpose<<<768, 256, 0, stream>>>(v, vt);
  k_attn<<<768, 256, 0, stream>>>(q, k, vt, attn_bias, ob);
  k_gemm_out<<<dim3(64, 12), 256, 0, stream>>>(ob, wob, b_out, out);
}

// Round 4
// 125.304 us; speedup vs baseline: 1.2886x; 1.2886x over previous
//
#include <hip/hip_runtime.h>
#include <hip/hip_bf16.h>
#include <stdint.h>

// Problem constants
#define B_ 4
#define L_ 1024
#define D_ 768
#define H_ 12
#define HD_ 64
#define M_ 4096     // B*L
#define N3_ 2304    // 3*D

typedef float f32x4 __attribute__((ext_vector_type(4)));
typedef float f32x4v __attribute__((ext_vector_type(4)));
typedef short bf16x8 __attribute__((ext_vector_type(8)));
typedef unsigned short u16;
typedef u16 u16x8 __attribute__((ext_vector_type(8)));
typedef u16 u16x4 __attribute__((ext_vector_type(4)));
typedef uint32_t u32x2 __attribute__((ext_vector_type(2)));

#define AS3 __attribute__((address_space(3)))
#define AS1 __attribute__((address_space(1)))

__device__ __forceinline__ void gll16(const void* g, void* l) {
  __builtin_amdgcn_global_load_lds((const AS1 void*)g, (AS3 void*)l, 16, 0, 0);
}

// fp32 -> bf16 round-to-nearest-even (finite data)
__device__ __forceinline__ u16 f2bf(float f) {
  uint32_t u = __builtin_bit_cast(uint32_t, f);
  u += 0x7fffu + ((u >> 16) & 1u);
  return (u16)(u >> 16);
}

// ---------------- fused conversion kernel (3 tensors, fp32 -> bf16) ---------
__global__ void k_cvt3(const float* __restrict__ a, u16* __restrict__ ao, int na4,
                       const float* __restrict__ b, u16* __restrict__ bo, int nb4,
                       const float* __restrict__ c, u16* __restrict__ co, int nc4) {
  int i = blockIdx.x * 256 + threadIdx.x;
  const float* src;
  u16* dst;
  if (i < na4) {
    src = a; dst = ao;
  } else if (i < na4 + nb4) {
    src = b; dst = bo; i -= na4;
  } else if (i < na4 + nb4 + nc4) {
    src = c; dst = co; i -= na4 + nb4;
  } else {
    return;
  }
  f32x4v v = ((const f32x4v*)src)[i];
  u16x4 o;
  o.x = f2bf(v.x); o.y = f2bf(v.y); o.z = f2bf(v.z); o.w = f2bf(v.w);
  ((u16x4*)dst)[i] = o;
}

// ---------------- GEMM1: qkv = x @ w_in^T + b_in -> Q,K,V bf16 [B,H,L,64] ----
__global__ __launch_bounds__(256) void k_gemm_qkv(
    const u16* __restrict__ Xb, const u16* __restrict__ Wb,
    const float* __restrict__ b_in,
    u16* __restrict__ gQ, u16* __restrict__ gK, u16* __restrict__ gV) {
  __shared__ u16 As[128 * 64];
  __shared__ u16 Bs[128 * 64];
  const int tid = threadIdx.x;
  const int lane = tid & 63;
  const int w = tid >> 6;
  const int wm = (w >> 1) * 64;
  const int wn = (w & 1) * 64;
  const int lr = lane & 15;
  const int lg = lane >> 4;
  const int m0 = blockIdx.x * 128;
  const int n0 = blockIdx.y * 128;

  f32x4 acc[4][4];
#pragma unroll
  for (int i = 0; i < 4; ++i)
#pragma unroll
    for (int j = 0; j < 4; ++j) acc[i][j] = (f32x4){0.f, 0.f, 0.f, 0.f};

  for (int kt = 0; kt < 12; ++kt) {
    __syncthreads();
#pragma unroll
    for (int i = 0; i < 4; ++i) {
      int seg = i * 256 + tid;
      int row = seg >> 3;
      int sl = (seg & 7) ^ (row & 7);
      gll16(Xb + (size_t)(m0 + row) * 768 + kt * 64 + sl * 8, (char*)As + seg * 16);
      gll16(Wb + (size_t)(n0 + row) * 768 + kt * 64 + sl * 8, (char*)Bs + seg * 16);
    }
    __syncthreads();
#pragma unroll
    for (int kh = 0; kh < 2; ++kh) {
      bf16x8 af[4], bfr[4];
#pragma unroll
      for (int t = 0; t < 4; ++t) {
        int ra = wm + t * 16 + lr;
        af[t] = *(const bf16x8*)((const char*)As + ra * 128 +
                                 ((kh * 64 + lg * 16) ^ ((ra & 7) << 4)));
        int rb = wn + t * 16 + lr;
        bfr[t] = *(const bf16x8*)((const char*)Bs + rb * 128 +
                                  ((kh * 64 + lg * 16) ^ ((rb & 7) << 4)));
      }
#pragma unroll
      for (int mi = 0; mi < 4; ++mi)
#pragma unroll
        for (int ni = 0; ni < 4; ++ni)
          acc[mi][ni] = __builtin_amdgcn_mfma_f32_16x16x32_bf16(
              af[mi], bfr[ni], acc[mi][ni], 0, 0, 0);
    }
  }
  // epilogue: +b_in, scale q, scatter to [B,H,L,64] bf16
  const int sec = blockIdx.y / 6;  // 0=q,1=k,2=v
  u16* dst = sec == 0 ? gQ : (sec == 1 ? gK : gV);
  const float scale = sec == 0 ? 0.125f : 1.0f;
#pragma unroll
  for (int ni = 0; ni < 4; ++ni) {
    int e = n0 + wn + ni * 16 + lr;  // 0..2303
    float bias = b_in[e];
    int es = e - sec * 768;
    int h = es >> 6, d = es & 63;
#pragma unroll
    for (int mi = 0; mi < 4; ++mi) {
#pragma unroll
      for (int j = 0; j < 4; ++j) {
        int m = m0 + wm + mi * 16 + lg * 4 + j;
        int bb = m >> 10, lq = m & 1023;
        float vv = (acc[mi][ni][j] + bias) * scale;
        dst[(size_t)((bb * 12 + h) * 1024 + lq) * 64 + d] = f2bf(vv);
      }
    }
  }
}

// ---------------- V transpose: [B,H,L,64] -> [B,H,64,L] ---------------------
__global__ __launch_bounds__(256) void k_transpose(const u16* __restrict__ V,
                                                   u16* __restrict__ Vt) {
  __shared__ u16 t[64][66];
  const int tid = threadIdx.x;
  const int bh = blockIdx.x >> 4;
  const int kv0 = (blockIdx.x & 15) * 64;
  {
    int r = tid >> 2, c0 = (tid & 3) * 16;
    const u16* src = V + (size_t)(bh * 1024 + kv0 + r) * 64 + c0;
#pragma unroll
    for (int p = 0; p < 2; ++p) {
      u16x8 x = *(const u16x8*)(src + p * 8);
#pragma unroll
      for (int e = 0; e < 8; ++e) t[r][c0 + p * 8 + e] = x[e];
    }
  }
  __syncthreads();
  {
    int d = tid >> 2, k0 = (tid & 3) * 16;
    u16* dst = Vt + (size_t)(bh * 64 + d) * 1024 + kv0 + k0;
#pragma unroll
    for (int p = 0; p < 2; ++p) {
      u16x8 o;
#pragma unroll
      for (int e = 0; e < 8; ++e) o[e] = t[k0 + p * 8 + e][d];
      *(u16x8*)(dst + p * 8) = o;
    }
  }
}

// ---------------- fused flash attention -------------------------------------
// Swapped QK^T (lane-local softmax) + LDS-staged K/V (gll16, double-buffered,
// counted-vmcnt barrier so bias loads stay in flight across it) + depth-2
// register bias prefetch (lane-matched f32x4 nontemporal loads).
__global__ __launch_bounds__(256) void k_attn(
    const u16* __restrict__ gQ, const u16* __restrict__ gK,
    const u16* __restrict__ gVt, const float* __restrict__ gBias,
    u16* __restrict__ gO) {
  __shared__ u16 Ks[2][64 * 64];   // [kv][d], rows 128B, src pre-swizzled
  __shared__ u16 Vs[2][64 * 64];   // [d][kv]
  __shared__ f32x4 PlV[4][128];    // per-wave 2KB P bounce
  const int tid = threadIdx.x;
  const int lane = tid & 63;
  const int w = tid >> 6;
  const int lr = lane & 15;
  const int lg = lane >> 4;
  // XCD-bijective swizzle: 768 = 8 XCDs x 96; the 16 q-blocks sharing one
  // (b,h)'s K/V land on one XCD -> K/V stay L2-resident.
  const int lb = (blockIdx.x & 7) * 96 + (blockIdx.x >> 3);
  const int bh = lb >> 4;
  const int q0 = (lb & 15) * 64;
  const int qr = q0 + w * 16;  // wave's q-row base; lane's q-row = qr + lr

// K/V tile stage: 2 gll16 each (8KB per tile), linear LDS dest, swizzled src
#define STAGE_KV(buf, kv0)                                                     \
  do {                                                                         \
    _Pragma("unroll") for (int i_ = 0; i_ < 2; ++i_) {                         \
      int seg_ = i_ * 256 + tid;                                               \
      int row_ = seg_ >> 3;                                                    \
      int sl_ = (seg_ & 7) ^ (row_ & 7);                                       \
      gll16(gK + (size_t)(bh * 1024 + (kv0) + row_) * 64 + sl_ * 8,            \
            (char*)Ks[buf] + seg_ * 16);                                       \
      gll16(gVt + (size_t)(bh * 64 + row_) * 1024 + (kv0) + sl_ * 8,           \
            (char*)Vs[buf] + seg_ * 16);                                       \
    }                                                                          \
  } while (0)

// Lane-matched bias loads: lane (lr,lg) needs bias[q=qr+lr][kv0+ni*16+lg*4 ..+3]
#define BIAS_LOAD(dst, kv0)                                                    \
  do {                                                                         \
    _Pragma("unroll") for (int ni_ = 0; ni_ < 4; ++ni_) {                      \
      dst[ni_] = __builtin_nontemporal_load(                                   \
          (const f32x4*)(bline + (kv0) + ni_ * 16 + lg * 4));                  \
    }                                                                          \
  } while (0)

  const float* bline = gBias + (size_t)(bh * 1024 + qr + lr) * 1024;

  // Q as B-operand: rows q = qr+lr, k chunk lg*8 (pre-scaled by 1/8)
  bf16x8 qa[2];
#pragma unroll
  for (int kh = 0; kh < 2; ++kh)
    qa[kh] = *(const bf16x8*)(gQ + (size_t)(bh * 1024 + qr + lr) * 64 + kh * 32 + lg * 8);

  f32x4 oacc[4];
#pragma unroll
  for (int dt = 0; dt < 4; ++dt) oacc[dt] = (f32x4){0.f, 0.f, 0.f, 0.f};
  float mrow = -1e30f, lrow = 0.f;

  char* plw = (char*)PlV[w];
  const int swz = (lr & 7) << 4;

  // prologue: stage KV(0); prefetch bias tiles 0,1
  STAGE_KV(0, 0);
  f32x4 bcur[4], bnext[4];
  BIAS_LOAD(bcur, 0);
  BIAS_LOAD(bnext, 64);
  asm volatile("s_waitcnt vmcnt(8)" ::: "memory");  // KV(0) done; bias in flight
  __builtin_amdgcn_s_barrier();

#pragma unroll 2
  for (int t = 0; t < 16; ++t) {
    const int cur = t & 1;

    if (t < 15) STAGE_KV(cur ^ 1, (t + 1) * 64);  // 4 gll16, waited at tile end
    f32x4 bn[4];
    if (t < 14) BIAS_LOAD(bn, (t + 2) * 64);      // 4 loads, waited 2 tiles later

    // S^T = K Q^T : s[ni][j] = S[kv = ni*16+lg*4+j][q = qr+lr]
    f32x4 s[4];
#pragma unroll
    for (int ni = 0; ni < 4; ++ni) s[ni] = (f32x4){0.f, 0.f, 0.f, 0.f};
    __builtin_amdgcn_s_setprio(1);
#pragma unroll
    for (int kh = 0; kh < 2; ++kh)
#pragma unroll
      for (int ni = 0; ni < 4; ++ni) {
        int rk = ni * 16 + lr;
        bf16x8 kb = *(const bf16x8*)((const char*)Ks[cur] + rk * 128 +
                                     ((kh * 64 + lg * 16) ^ ((rk & 7) << 4)));
        s[ni] = __builtin_amdgcn_mfma_f32_16x16x32_bf16(kb, qa[kh], s[ni], 0, 0, 0);
      }
    __builtin_amdgcn_s_setprio(0);

    // + bias (depth-2 prefetched registers)
#pragma unroll
    for (int ni = 0; ni < 4; ++ni) s[ni] += bcur[ni];

    // lane-local online softmax for q-row (qr+lr)
    float mx0 = fmaxf(fmaxf(s[0][0], s[0][1]), fmaxf(s[0][2], s[0][3]));
    float mx1 = fmaxf(fmaxf(s[1][0], s[1][1]), fmaxf(s[1][2], s[1][3]));
    float mx2 = fmaxf(fmaxf(s[2][0], s[2][1]), fmaxf(s[2][2], s[2][3]));
    float mx3 = fmaxf(fmaxf(s[3][0], s[3][1]), fmaxf(s[3][2], s[3][3]));
    float vmax = fmaxf(fmaxf(mx0, mx1), fmaxf(mx2, mx3));
    vmax = fmaxf(vmax, __shfl_xor(vmax, 16));
    vmax = fmaxf(vmax, __shfl_xor(vmax, 32));
    float mnew = fmaxf(mrow, vmax);
    float al = __expf(mrow - mnew);
    mrow = mnew;
#pragma unroll
    for (int ni = 0; ni < 4; ++ni)
#pragma unroll
      for (int j = 0; j < 4; ++j) s[ni][j] = __expf(s[ni][j] - mnew);
    float r0 = (s[0][0] + s[0][1]) + (s[0][2] + s[0][3]);
    float r1 = (s[1][0] + s[1][1]) + (s[1][2] + s[1][3]);
    float r2 = (s[2][0] + s[2][1]) + (s[2][2] + s[2][3]);
    float r3 = (s[3][0] + s[3][1]) + (s[3][2] + s[3][3]);
    float rs = (r0 + r1) + (r2 + r3);
    rs += __shfl_xor(rs, 16);
    rs += __shfl_xor(rs, 32);
    lrow = lrow * al + rs;

    // broadcast al from lane (lr = q) to the oacc owners (q = lg*4+j)
    f32x4 av;
#pragma unroll
    for (int j = 0; j < 4; ++j) av[j] = __shfl(al, (lane & 48) | (lg * 4 + j));
#pragma unroll
    for (int dt = 0; dt < 4; ++dt) oacc[dt] *= av;

    // P pack -> per-wave swizzled LDS (b64), read back as A-fragment, PV
#pragma unroll
    for (int ni = 0; ni < 4; ++ni) {
      uint32_t w0 = (uint32_t)f2bf(s[ni][0]) | ((uint32_t)f2bf(s[ni][1]) << 16);
      uint32_t w1 = (uint32_t)f2bf(s[ni][2]) | ((uint32_t)f2bf(s[ni][3]) << 16);
      u32x2 pv = {w0, w1};
      *(u32x2*)(plw + lr * 128 + ((ni * 32 + lg * 8) ^ swz)) = pv;
    }
    __builtin_amdgcn_s_setprio(1);
#pragma unroll
    for (int kh = 0; kh < 2; ++kh) {
      bf16x8 pa = *(const bf16x8*)(plw + lr * 128 + ((kh * 64 + lg * 16) ^ swz));
#pragma unroll
      for (int dt = 0; dt < 4; ++dt) {
        int rv = dt * 16 + lr;
        bf16x8 vb = *(const bf16x8*)((const char*)Vs[cur] + rv * 128 +
                                     ((kh * 64 + lg * 16) ^ ((rv & 7) << 4)));
        oacc[dt] = __builtin_amdgcn_mfma_f32_16x16x32_bf16(pa, vb, oacc[dt], 0, 0, 0);
      }
    }
    __builtin_amdgcn_s_setprio(0);

    // rotate bias prefetch registers
    if (t < 14) {
#pragma unroll
      for (int z = 0; z < 4; ++z) { bcur[z] = bnext[z]; bnext[z] = bn[z]; }
    } else {
#pragma unroll
      for (int z = 0; z < 4; ++z) bcur[z] = bnext[z];
    }

    // tile-end: publish KV(t+1); keep newest bias loads in flight
    if (t < 14) {
      asm volatile("s_waitcnt vmcnt(4) lgkmcnt(0)" ::: "memory");
      __builtin_amdgcn_s_barrier();
    } else if (t < 15) {
      asm volatile("s_waitcnt vmcnt(0) lgkmcnt(0)" ::: "memory");
      __builtin_amdgcn_s_barrier();
    }
  }

  // normalize + store O bf16 [B,L,D]; inv broadcast like al
  float inv = 1.0f / lrow;
  f32x4 iv;
#pragma unroll
  for (int j = 0; j < 4; ++j) iv[j] = __shfl(inv, (lane & 48) | (lg * 4 + j));
  const int bg = bh / 12, h = bh % 12;
#pragma unroll
  for (int j = 0; j < 4; ++j) {
    int row = qr + lg * 4 + j;
#pragma unroll
    for (int dt = 0; dt < 4; ++dt) {
      gO[(size_t)(bg * 1024 + row) * 768 + h * 64 + dt * 16 + lr] =
          f2bf(oacc[dt][j] * iv[j]);
    }
  }
#undef STAGE_KV
#undef BIAS_LOAD
}

// ---------------- GEMM2: out = O @ w_out^T + b_out (fp32 out), 64x64 tiles --
__global__ __launch_bounds__(256) void k_gemm_out(
    const u16* __restrict__ Ob, const u16* __restrict__ Wb,
    const float* __restrict__ b_out, float* __restrict__ out) {
  __shared__ u16 As[64 * 64];
  __shared__ u16 Bs[64 * 64];
  const int tid = threadIdx.x;
  const int lane = tid & 63;
  const int w = tid >> 6;
  const int wm = (w >> 1) * 32;
  const int wn = (w & 1) * 32;
  const int lr = lane & 15;
  const int lg = lane >> 4;
  const int m0 = blockIdx.x * 64;
  const int n0 = blockIdx.y * 64;

  f32x4 acc[2][2];
#pragma unroll
  for (int i = 0; i < 2; ++i)
#pragma unroll
    for (int j = 0; j < 2; ++j) acc[i][j] = (f32x4){0.f, 0.f, 0.f, 0.f};

  for (int kt = 0; kt < 12; ++kt) {
    __syncthreads();
#pragma unroll
    for (int i = 0; i < 2; ++i) {
      int seg = i * 256 + tid;
      int row = seg >> 3;
      int sl = (seg & 7) ^ (row & 7);
      gll16(Ob + (size_t)(m0 + row) * 768 + kt * 64 + sl * 8, (char*)As + seg * 16);
      gll16(Wb + (size_t)(n0 + row) * 768 + kt * 64 + sl * 8, (char*)Bs + seg * 16);
    }
    __syncthreads();
#pragma unroll
    for (int kh = 0; kh < 2; ++kh) {
      bf16x8 af[2], bfr[2];
#pragma unroll
      for (int t = 0; t < 2; ++t) {
        int ra = wm + t * 16 + lr;
        af[t] = *(const bf16x8*)((const char*)As + ra * 128 +
                                 ((kh * 64 + lg * 16) ^ ((ra & 7) << 4)));
        int rb = wn + t * 16 + lr;
        bfr[t] = *(const bf16x8*)((const char*)Bs + rb * 128 +
                                  ((kh * 64 + lg * 16) ^ ((rb & 7) << 4)));
      }
#pragma unroll
      for (int mi = 0; mi < 2; ++mi)
#pragma unroll
        for (int ni = 0; ni < 2; ++ni)
          acc[mi][ni] = __builtin_amdgcn_mfma_f32_16x16x32_bf16(
              af[mi], bfr[ni], acc[mi][ni], 0, 0, 0);
    }
  }
#pragma unroll
  for (int ni = 0; ni < 2; ++ni) {
    int n = n0 + wn + ni * 16 + lr;
    float bias = b_out[n];
#pragma unroll
    for (int mi = 0; mi < 2; ++mi) {
#pragma unroll
      for (int j = 0; j < 4; ++j) {
        int m = m0 + wm + mi * 16 + lg * 4 + j;
        out[(size_t)m * 768 + n] = acc[mi][ni][j] + bias;
      }
    }
  }
}

extern "C" void kernel_launch(void* const* d_in, const int* in_sizes, int n_in,
                              void* d_out, int out_size, void* d_ws, size_t ws_size,
                              hipStream_t stream) {
  const float* x = (const float*)d_in[0];
  const float* attn_bias = (const float*)d_in[1];
  const float* w_in = (const float*)d_in[2];
  const float* b_in = (const float*)d_in[3];
  const float* w_out = (const float*)d_in[4];
  const float* b_out = (const float*)d_in[5];
  float* out = (float*)d_out;

  char* ws = (char*)d_ws;
  size_t off = 0;
  u16* xb = (u16*)(ws + off);  off += (size_t)M_ * D_ * 2;
  u16* wib = (u16*)(ws + off); off += (size_t)N3_ * D_ * 2;
  u16* wob = (u16*)(ws + off); off += (size_t)D_ * D_ * 2;
  u16* q = (u16*)(ws + off);   off += (size_t)48 * 1024 * 64 * 2;
  u16* k = (u16*)(ws + off);   off += (size_t)48 * 1024 * 64 * 2;
  u16* v = (u16*)(ws + off);   off += (size_t)48 * 1024 * 64 * 2;
  u16* vt = (u16*)(ws + off);  off += (size_t)48 * 1024 * 64 * 2;
  u16* ob = (u16*)(ws + off);  off += (size_t)M_ * D_ * 2;

  const int na4 = (M_ * D_) / 4;
  const int nb4 = (N3_ * D_) / 4;
  const int nc4 = (D_ * D_) / 4;
  k_cvt3<<<(na4 + nb4 + nc4 + 255) / 256, 256, 0, stream>>>(
      x, xb, na4, w_in, wib, nb4, w_out, wob, nc4);
  k_gemm_qkv<<<dim3(32, 18), 256, 0, stream>>>(xb, wib, b_in, q, k, v);
  k_transpose<<<768, 256, 0, stream>>>(v, vt);
  k_attn<<<768, 256, 0, stream>>>(q, k, vt, attn_bias, ob);
  k_gemm_out<<<dim3(64, 12), 256, 0, stream>>>(ob, wob, b_out, out);
}